// Round 10
// baseline (51.589 us; speedup 1.0000x reference)
//
#include <hip/hip_runtime.h>

#define B_ 4
#define N_ 2048
#define IND_ 128
#define H_ 4
#define D_ 64
#define HD_ 256
#define LEAKY 0.2f
#define BNEPS 1e-5f
#define LOG2E 1.44269504088896340736f

typedef float f32x4 __attribute__((ext_vector_type(4)));
typedef short s16x8 __attribute__((ext_vector_type(8)));
typedef unsigned int u32x2 __attribute__((ext_vector_type(2)));
typedef unsigned int u32x4 __attribute__((ext_vector_type(4)));

static __device__ __forceinline__ unsigned short f2bf(float f) {
  unsigned u = __builtin_bit_cast(unsigned, f);
  u = (u + 0x7fffu + ((u >> 16) & 1u)) >> 16;   // RNE
  return (unsigned short)u;
}

// ------- Kernel A (fused): [gemm blocks 0..511] || [pack blocks 512..] ----
// gemm role: Wh^T = W^T @ h^T via MFMA, A-frags read straight from W (L2).
// D-layout (col=n, row=ch) lands directly in wht[bh][d][n]; src/dst (log2e-
// scaled) from fp32 acc. pack role: adjacency bitmask + zero accumulators.
__global__ __launch_bounds__(256) void k_pre(const int* __restrict__ adj,
                                             const float* __restrict__ W,
                                             const float* __restrict__ h,
                                             const float* __restrict__ a,
                                             unsigned* __restrict__ bits,
                                             float* __restrict__ zbuf,
                                             unsigned short* __restrict__ wht,
                                             float* __restrict__ src,
                                             float* __restrict__ dst) {
  int t = threadIdx.x;
  if (blockIdx.x >= 512) {          // ---- pack role
    int pidx = blockIdx.x - 512;
    if (pidx == 0) {
      for (int i = t; i < 512; i += 256) zbuf[i] = 0.f;   // chsum|chsq
    }
    int idx = pidx * 256 + t;       // flat over N*N (row-major)
    int val = adj[idx] != 0;
    unsigned long long mm = __ballot(val);
    int lane = t & 63;
    if (lane == 0)       bits[idx >> 5] = (unsigned)mm;
    else if (lane == 32) bits[idx >> 5] = (unsigned)(mm >> 32);
    return;
  }
  // ---- gemm role: 512 blocks x 16 rows(n); wave w owns head w's 64 ch
  int w = t >> 6, lane = t & 63, m = lane & 15, g = lane >> 4;
  int r0 = blockIdx.x * 16;                    // flat row base in [0, B*N)
  int b = r0 >> 11, n0 = r0 & 2047;
  int hh = w;

  // A-frags direct from W[k][ch]: ch = w*64+chf*16+m, k = ks*32+g*8+e
  s16x8 Af[4][4];
#pragma unroll
  for (int chf = 0; chf < 4; chf++) {
    int chl = w * 64 + chf * 16 + m;
#pragma unroll
    for (int ks = 0; ks < 4; ks++) {
      int k0 = ks * 32 + g * 8;
      u32x4 au;
#pragma unroll
      for (int e2 = 0; e2 < 4; e2++) {
        float lo = W[(size_t)(k0 + 2 * e2) * 256 + chl];
        float hi = W[(size_t)(k0 + 2 * e2 + 1) * 256 + chl];
        unsigned rr_;
        asm("v_cvt_pk_bf16_f32 %0, %1, %2" : "=v"(rr_) : "v"(lo), "v"(hi));
        au[e2] = rr_;
      }
      Af[chf][ks] = __builtin_bit_cast(s16x8, au);
    }
  }
  // B-frags: h[r0+m][ks*32 + g*8 ..+8] f32 -> bf16 pack
  s16x8 Bf[4];
#pragma unroll
  for (int ks = 0; ks < 4; ks++) {
    const float* hp = h + (size_t)(r0 + m) * 128 + ks * 32 + g * 8;
    f32x4 h0 = *(const f32x4*)hp;
    f32x4 h1 = *(const f32x4*)(hp + 4);
    u32x4 bu;
#pragma unroll
    for (int e = 0; e < 4; e++) {
      float lo = (e < 2) ? h0[2 * e] : h1[2 * e - 4];
      float hi = (e < 2) ? h0[2 * e + 1] : h1[2 * e - 3];
      unsigned rr_;
      asm("v_cvt_pk_bf16_f32 %0, %1, %2" : "=v"(rr_) : "v"(lo), "v"(hi));
      bu[e] = rr_;
    }
    Bf[ks] = __builtin_bit_cast(s16x8, bu);
  }

  f32x4 acc[4];
#pragma unroll
  for (int chf = 0; chf < 4; chf++) acc[chf] = (f32x4){0.f, 0.f, 0.f, 0.f};
#pragma unroll
  for (int ks = 0; ks < 4; ks++)
#pragma unroll
    for (int chf = 0; chf < 4; chf++)
      acc[chf] = __builtin_amdgcn_mfma_f32_16x16x32_bf16(Af[chf][ks], Bf[ks], acc[chf], 0, 0, 0);

  // write wht: lane holds ch = w*64 + chf*16 + g*4 + reg, n = n0 + m
  size_t obase = ((size_t)((b * 4 + hh) * 64)) * 2048 + n0 + m;
#pragma unroll
  for (int chf = 0; chf < 4; chf++) {
    int d = chf * 16 + g * 4;
#pragma unroll
    for (int reg = 0; reg < 4; reg++)
      wht[obase + (size_t)(d + reg) * 2048] = f2bf(acc[chf][reg]);
  }

  // src/dst scalars for head hh from fp32 acc (pre-scaled by log2e)
  float sv = 0.f, dv = 0.f;
#pragma unroll
  for (int chf = 0; chf < 4; chf++)
#pragma unroll
    for (int reg = 0; reg < 4; reg++) {
      int d = chf * 16 + g * 4 + reg;
      float whv = acc[chf][reg];
      sv = fmaf(whv, a[hh * 128 + d] * LOG2E, sv);
      dv = fmaf(whv, a[hh * 128 + 64 + d] * LOG2E, dv);
    }
  sv += __shfl_xor(sv, 16); sv += __shfl_xor(sv, 32);
  dv += __shfl_xor(dv, 16); dv += __shfl_xor(dv, 32);
  if (g == 0) {
    src[(size_t)(b * 4 + hh) * 2048 + n0 + m] = sv;
    dst[(size_t)(b * 4 + hh) * 2048 + n0 + m] = dv;
  }
}

// ---------------- Kernel C: flash attention, j split across wave-halves ---
// 512 threads: waves 0-3 handle j in [0,1024), waves 4-7 j in [1024,2048).
// adjacency: per-lane 8B register prefetch from L2 (no LDS staging).
// Factorized scores p = max(Af_i*u_j, Bf_i*v_j); den via 5th MFMA.
// LDS 50KB -> 3 blocks/CU (6 waves/SIMD).
__global__ __launch_bounds__(512, 6) void k_attn(const unsigned* __restrict__ adjb,
                                              const unsigned short* __restrict__ wht,
                                              const float* __restrict__ src,
                                              const float* __restrict__ dst,
                                              float* __restrict__ hnew,
                                              float* __restrict__ chsum,
                                              float* __restrict__ chsq) {
  __shared__ u32x4 whb4[2048];            // 2 halves x 2 dbuf x 8KB, XOR-swizzled
  __shared__ float ul[2048], vl[2048];    // 16KB: u_j = 2^dstL, v_j = 2^(.2 dstL)
  __shared__ float redS[256], redQ[256];

  int t = threadIdx.x;
  int bid = blockIdx.x;
  int bh = bid & 15, it = bid >> 4;       // 16 consecutive blocks share adj rows (L2)
  int b = bh >> 2, hh = bh & 3;
  int i0 = it * 64;
  int w8 = t >> 6, half = w8 >> 2, w = w8 & 3;
  int lane = t & 63, m = lane & 15, g = lane >> 4;

  {
    f32x4 dv = ((const f32x4*)(dst + (size_t)bh * 2048))[t];
    f32x4 uu, vv;
#pragma unroll
    for (int e = 0; e < 4; e++) {
      uu[e] = __builtin_amdgcn_exp2f(dv[e]);
      vv[e] = __builtin_amdgcn_exp2f(0.2f * dv[e]);
    }
    ((f32x4*)ul)[t] = uu;
    ((f32x4*)vl)[t] = vv;
  }

  int row_i = i0 + w * 16 + m;            // A-frag row this lane fills
  float srcL = src[(size_t)bh * 2048 + row_i];
  float Af = __builtin_amdgcn_exp2f(srcL);
  float Bf = __builtin_amdgcn_exp2f(LEAKY * srcL);

  s16x8 bones;
#pragma unroll
  for (int e = 0; e < 8; e++) bones[e] = (short)0x3F80;    // bf16 1.0

  f32x4 acc[4], accd;
#pragma unroll
  for (int db = 0; db < 4; db++) acc[db] = (f32x4){0.f, 0.f, 0.f, 0.f};
  accd = (f32x4){0.f, 0.f, 0.f, 0.f};

  char* wbase = (char*)whb4 + half * 16384;
  int ts = t & 255;
  int r_ = ts >> 2, ch_ = ts & 3;
  int jtbase = half * 16;
  const char* gbase = (const char*)(wht + (size_t)(bh * 64 + r_) * 2048) + jtbase * 128;
  int sw = (r_ & 7) << 4;
  u32x4 R0, R1;
  const u32x2* adjrow = (const u32x2*)(adjb + (size_t)row_i * 64 + jtbase * 2);

#define LOADT(jt_) { const u32x4* gp = (const u32x4*)(gbase + (jt_) * 128 + ch_ * 32); \
                     R0 = gp[0]; R1 = gp[1]; }
#define WRITET(pb_) { char* wb_ = (pb_); \
                      *(u32x4*)(wb_ + r_ * 128 + ((ch_ * 32) ^ sw)) = R0; \
                      *(u32x4*)(wb_ + r_ * 128 + ((ch_ * 32 + 16) ^ sw)) = R1; }

  LOADT(0); WRITET(wbase); LOADT(1);
  u32x2 adjw2 = adjrow[0];                // adjacency words for jt=0

  for (int jt = 0; jt < 16; jt++) {
    int cur = jt & 1;
    __syncthreads();                      // drains prefetch vmem + dbuf writes
    if (jt < 15) WRITET(wbase + (cur ^ 1) * 8192);   // tile jt+1 -> other buf
    if (jt < 14) LOADT(jt + 2);                      // issue tile jt+2 loads
    u32x2 adjnx;
    if (jt < 15) adjnx = adjrow[jt + 1];             // prefetch next adj words
    const char* wbufc = wbase + cur * 8192;
    int jglob = jtbase + jt;

#pragma unroll
    for (int ks = 0; ks < 2; ks++) {
      unsigned bits = (adjw2[ks] >> (g * 8)) & 0xffu;
      const float* up = &ul[jglob * 64 + ks * 32 + g * 8];
      const float* vp = &vl[jglob * 64 + ks * 32 + g * 8];
      f32x4 u0 = *(const f32x4*)up, u1 = *(const f32x4*)(up + 4);
      f32x4 v0 = *(const f32x4*)vp, v1 = *(const f32x4*)(vp + 4);
      float pm[8];
#pragma unroll
      for (int e = 0; e < 8; e++) {
        float ue = (e < 4) ? u0[e] : u1[e - 4];
        float ve = (e < 4) ? v0[e] : v1[e - 4];
        float p = fmaxf(Af * ue, Bf * ve);            // leaky-exp, factorized
        unsigned keep = (unsigned)(((int)(bits << (31 - e))) >> 31);
        pm[e] = __builtin_bit_cast(float, __builtin_bit_cast(unsigned, p) & keep);
      }
      u32x4 afu;
#pragma unroll
      for (int e2 = 0; e2 < 4; e2++) {
        unsigned rr_;
        asm("v_cvt_pk_bf16_f32 %0, %1, %2" : "=v"(rr_) : "v"(pm[2 * e2]), "v"(pm[2 * e2 + 1]));
        afu[e2] = rr_;
      }
      s16x8 af = __builtin_bit_cast(s16x8, afu);
#pragma unroll
      for (int db = 0; db < 4; db++) {
        int dl = db * 16 + m;
        int off = dl * 128 + ((ks * 64 + g * 16) ^ ((dl & 7) << 4));
        s16x8 bf = *(const s16x8*)(wbufc + off);
        acc[db] = __builtin_amdgcn_mfma_f32_16x16x32_bf16(af, bf, acc[db], 0, 0, 0);
      }
      accd = __builtin_amdgcn_mfma_f32_16x16x32_bf16(af, bones, accd, 0, 0, 0);
    }
    adjw2 = adjnx;
  }
#undef LOADT
#undef WRITET

  __syncthreads();                        // whb4 dead; reuse as combine buffer
  float* accl = (float*)whb4;             // [row][65] (col 64 = den)
  if (half == 1) {
#pragma unroll
    for (int db = 0; db < 4; db++)
#pragma unroll
      for (int r = 0; r < 4; r++)
        accl[(w * 16 + 4 * g + r) * 65 + db * 16 + m] = acc[db][r];
    if (m == 0) {
#pragma unroll
      for (int r = 0; r < 4; r++)
        accl[(w * 16 + 4 * g + r) * 65 + 64] = accd[r];
    }
  }
  __syncthreads();

  if (half == 0) {
#pragma unroll
    for (int db = 0; db < 4; db++)
#pragma unroll
      for (int r = 0; r < 4; r++)
        acc[db][r] += accl[(w * 16 + 4 * g + r) * 65 + db * 16 + m];
    float inv[4];
#pragma unroll
    for (int r = 0; r < 4; r++) {
      float dtot = accd[r] + accl[(w * 16 + 4 * g + r) * 65 + 64];
      inv[r] = dtot > 0.f ? 1.0f / dtot : 0.f;  // all-masked row -> zeros
    }

    float sums[4] = {0.f, 0.f, 0.f, 0.f}, sqs[4] = {0.f, 0.f, 0.f, 0.f};
#pragma unroll
    for (int r = 0; r < 4; r++) {
      int n = i0 + w * 16 + 4 * g + r;
#pragma unroll
      for (int db = 0; db < 4; db++) {
        float val = acc[db][r] * inv[r];
        hnew[(size_t)(b * 2048 + n) * 256 + hh * 64 + db * 16 + m] = val;
        sums[db] += val;
        sqs[db] += val * val;
      }
    }
#pragma unroll
    for (int db = 0; db < 4; db++) {
      sums[db] += __shfl_xor(sums[db], 16); sums[db] += __shfl_xor(sums[db], 32);
      sqs[db]  += __shfl_xor(sqs[db], 16);  sqs[db]  += __shfl_xor(sqs[db], 32);
    }
    if (g == 0) {
#pragma unroll
      for (int db = 0; db < 4; db++) {
        redS[w * 64 + db * 16 + m] = sums[db];
        redQ[w * 64 + db * 16 + m] = sqs[db];
      }
    }
  }
  __syncthreads();
  if (t < 64) {
    float ts2 = redS[t] + redS[64 + t] + redS[128 + t] + redS[192 + t];
    float tq = redQ[t] + redQ[64 + t] + redQ[128 + t] + redQ[192 + t];
    atomicAdd(&chsum[hh * 64 + t], ts2);
    atomicAdd(&chsq[hh * 64 + t], tq);
  }
}

// ---------------- Kernel D: BN(+stats inline) + ELU -----------------------
__global__ __launch_bounds__(256) void k_bn_elu(const float* __restrict__ hnew,
                                                const float* __restrict__ chsum,
                                                const float* __restrict__ chsq,
                                                const float* __restrict__ gamma,
                                                const float* __restrict__ beta,
                                                float* __restrict__ out) {
  int idx4 = blockIdx.x * 256 + threadIdx.x;
  f32x4 x = ((const f32x4*)hnew)[idx4];
  int c0 = (idx4 * 4) & 255;
  f32x4 s = *(const f32x4*)(chsum + c0);
  f32x4 sq = *(const f32x4*)(chsq + c0);
  f32x4 gm = *(const f32x4*)(gamma + c0);
  f32x4 bt = *(const f32x4*)(beta + c0);
  f32x4 y;
#pragma unroll
  for (int e = 0; e < 4; e++) {
    float mean = s[e] * (1.0f / 8192.0f);
    float var = sq[e] * (1.0f / 8192.0f) - mean * mean;
    float sc = gm[e] * rsqrtf(var + BNEPS);
    float v = (x[e] - mean) * sc + bt[e];
    y[e] = v > 0.f ? v : expm1f(v);
  }
  ((f32x4*)out)[idx4] = y;
}

extern "C" void kernel_launch(void* const* d_in, const int* in_sizes, int n_in,
                              void* d_out, int out_size, void* d_ws, size_t ws_size,
                              hipStream_t stream) {
  const float* h = (const float*)d_in[0];
  const float* W = (const float*)d_in[1];
  const float* a = (const float*)d_in[2];
  const float* gamma = (const float*)d_in[3];
  const float* beta = (const float*)d_in[4];
  const int* adj = (const int*)d_in[5];

  char* ws = (char*)d_ws;
  unsigned* adjb = (unsigned*)ws;                                  // 512 KB
  unsigned short* wht = (unsigned short*)(ws + (512 << 10));       // 4 MB
  float* src = (float*)(ws + (512 << 10) + (4 << 20));             // 128 KB
  float* dst = src + 16 * 2048;                                    // 128 KB
  float* chsum = dst + 16 * 2048;                                  // 256
  float* chsq = chsum + 256;                                       // 256
  float* hnew = (float*)(ws + (512 << 10) + (5 << 20));            // 8 MB

  k_pre<<<512 + (N_ * N_) / 256, 256, 0, stream>>>(adj, W, h, a, adjb, chsum,
                                                   wht, src, dst);
  k_attn<<<B_ * H_ * (N_ / 64), 512, 0, stream>>>(adjb, wht, src, dst,
                                                  hnew, chsum, chsq);
  k_bn_elu<<<(B_ * N_ * HD_) / 1024, 256, 0, stream>>>(hnew, chsum, chsq,
                                                       gamma, beta, (float*)d_out);
}

// Round 11
// 50.954 us; speedup vs baseline: 1.0125x; 1.0125x over previous
//
#include <hip/hip_runtime.h>

#define B_ 4
#define N_ 2048
#define IND_ 128
#define H_ 4
#define D_ 64
#define HD_ 256
#define LEAKY 0.2f
#define BNEPS 1e-5f
#define LOG2E 1.44269504088896340736f

typedef float f32x4 __attribute__((ext_vector_type(4)));
typedef short s16x8 __attribute__((ext_vector_type(8)));
typedef unsigned int u32x2 __attribute__((ext_vector_type(2)));
typedef unsigned int u32x4 __attribute__((ext_vector_type(4)));

static __device__ __forceinline__ unsigned short f2bf(float f) {
  unsigned u = __builtin_bit_cast(unsigned, f);
  u = (u + 0x7fffu + ((u >> 16) & 1u)) >> 16;   // RNE
  return (unsigned short)u;
}

// Barrier WITHOUT the vmcnt(0) drain __syncthreads would emit: ds-op
// ordering needs lgkmcnt(0); global prefetch loads target registers, so
// vmcnt is enforced at their use by register dependence. (T4: never
// drain vmcnt to 0 in the main loop.)
#define BAR() do { asm volatile("s_waitcnt lgkmcnt(0)" ::: "memory"); \
                   __builtin_amdgcn_s_barrier(); } while (0)

// ------- Kernel A (fused): [gemm blocks 0..511] || [pack blocks 512..] ----
// gemm role: Wh^T = W^T @ h^T via MFMA, A-frags read straight from W (L2).
// D-layout (col=n, row=ch) lands directly in wht[bh][d][n]; src/dst (log2e-
// scaled) from fp32 acc. pack role: adjacency bitmask + zero accumulators.
__global__ __launch_bounds__(256) void k_pre(const int* __restrict__ adj,
                                             const float* __restrict__ W,
                                             const float* __restrict__ h,
                                             const float* __restrict__ a,
                                             unsigned* __restrict__ bits,
                                             float* __restrict__ zbuf,
                                             unsigned short* __restrict__ wht,
                                             float* __restrict__ src,
                                             float* __restrict__ dst) {
  int t = threadIdx.x;
  if (blockIdx.x >= 512) {          // ---- pack role
    int pidx = blockIdx.x - 512;
    if (pidx == 0) {
      for (int i = t; i < 512; i += 256) zbuf[i] = 0.f;   // chsum|chsq
    }
    int idx = pidx * 256 + t;       // flat over N*N (row-major)
    int val = adj[idx] != 0;
    unsigned long long mm = __ballot(val);
    int lane = t & 63;
    if (lane == 0)       bits[idx >> 5] = (unsigned)mm;
    else if (lane == 32) bits[idx >> 5] = (unsigned)(mm >> 32);
    return;
  }
  // ---- gemm role: 512 blocks x 16 rows(n); wave w owns head w's 64 ch
  int w = t >> 6, lane = t & 63, m = lane & 15, g = lane >> 4;
  int r0 = blockIdx.x * 16;                    // flat row base in [0, B*N)
  int b = r0 >> 11, n0 = r0 & 2047;
  int hh = w;

  // A-frags direct from W[k][ch]: ch = w*64+chf*16+m, k = ks*32+g*8+e
  s16x8 Af[4][4];
#pragma unroll
  for (int chf = 0; chf < 4; chf++) {
    int chl = w * 64 + chf * 16 + m;
#pragma unroll
    for (int ks = 0; ks < 4; ks++) {
      int k0 = ks * 32 + g * 8;
      u32x4 au;
#pragma unroll
      for (int e2 = 0; e2 < 4; e2++) {
        float lo = W[(size_t)(k0 + 2 * e2) * 256 + chl];
        float hi = W[(size_t)(k0 + 2 * e2 + 1) * 256 + chl];
        unsigned rr_;
        asm("v_cvt_pk_bf16_f32 %0, %1, %2" : "=v"(rr_) : "v"(lo), "v"(hi));
        au[e2] = rr_;
      }
      Af[chf][ks] = __builtin_bit_cast(s16x8, au);
    }
  }
  // B-frags: h[r0+m][ks*32 + g*8 ..+8] f32 -> bf16 pack
  s16x8 Bf[4];
#pragma unroll
  for (int ks = 0; ks < 4; ks++) {
    const float* hp = h + (size_t)(r0 + m) * 128 + ks * 32 + g * 8;
    f32x4 h0 = *(const f32x4*)hp;
    f32x4 h1 = *(const f32x4*)(hp + 4);
    u32x4 bu;
#pragma unroll
    for (int e = 0; e < 4; e++) {
      float lo = (e < 2) ? h0[2 * e] : h1[2 * e - 4];
      float hi = (e < 2) ? h0[2 * e + 1] : h1[2 * e - 3];
      unsigned rr_;
      asm("v_cvt_pk_bf16_f32 %0, %1, %2" : "=v"(rr_) : "v"(lo), "v"(hi));
      bu[e] = rr_;
    }
    Bf[ks] = __builtin_bit_cast(s16x8, bu);
  }

  f32x4 acc[4];
#pragma unroll
  for (int chf = 0; chf < 4; chf++) acc[chf] = (f32x4){0.f, 0.f, 0.f, 0.f};
#pragma unroll
  for (int ks = 0; ks < 4; ks++)
#pragma unroll
    for (int chf = 0; chf < 4; chf++)
      acc[chf] = __builtin_amdgcn_mfma_f32_16x16x32_bf16(Af[chf][ks], Bf[ks], acc[chf], 0, 0, 0);

  // write wht: lane holds ch = w*64 + chf*16 + g*4 + reg, n = n0 + m
  size_t obase = ((size_t)((b * 4 + hh) * 64)) * 2048 + n0 + m;
#pragma unroll
  for (int chf = 0; chf < 4; chf++) {
    int d = chf * 16 + g * 4;
#pragma unroll
    for (int reg = 0; reg < 4; reg++)
      wht[obase + (size_t)(d + reg) * 2048] = f2bf(acc[chf][reg]);
  }

  // src/dst scalars for head hh from fp32 acc (pre-scaled by log2e)
  float sv = 0.f, dv = 0.f;
#pragma unroll
  for (int chf = 0; chf < 4; chf++)
#pragma unroll
    for (int reg = 0; reg < 4; reg++) {
      int d = chf * 16 + g * 4 + reg;
      float whv = acc[chf][reg];
      sv = fmaf(whv, a[hh * 128 + d] * LOG2E, sv);
      dv = fmaf(whv, a[hh * 128 + 64 + d] * LOG2E, dv);
    }
  sv += __shfl_xor(sv, 16); sv += __shfl_xor(sv, 32);
  dv += __shfl_xor(dv, 16); dv += __shfl_xor(dv, 32);
  if (g == 0) {
    src[(size_t)(b * 4 + hh) * 2048 + n0 + m] = sv;
    dst[(size_t)(b * 4 + hh) * 2048 + n0 + m] = dv;
  }
}

// ---------------- Kernel C: flash attention, j split across wave-halves ---
// 512 threads: waves 0-3 handle j in [0,1024), waves 4-7 j in [1024,2048).
// adjacency: per-lane 8B register prefetch from L2 (no LDS staging).
// Factorized scores p = max(Af_i*u_j, Bf_i*v_j); den via 5th MFMA.
// In-loop barriers use counted waits (lgkmcnt only) so global prefetches
// stay in flight across barriers.
__global__ __launch_bounds__(512) void k_attn(const unsigned* __restrict__ adjb,
                                              const unsigned short* __restrict__ wht,
                                              const float* __restrict__ src,
                                              const float* __restrict__ dst,
                                              float* __restrict__ hnew,
                                              float* __restrict__ chsum,
                                              float* __restrict__ chsq) {
  __shared__ u32x4 whb4[2048];            // 2 halves x 2 dbuf x 8KB, XOR-swizzled
  __shared__ float ul[2048], vl[2048];    // 16KB: u_j = 2^dstL, v_j = 2^(.2 dstL)
  __shared__ float redS[256], redQ[256];

  int t = threadIdx.x;
  int bid = blockIdx.x;
  int bh = bid & 15, it = bid >> 4;       // 16 consecutive blocks share adj rows (L2)
  int b = bh >> 2, hh = bh & 3;
  int i0 = it * 64;
  int w8 = t >> 6, half = w8 >> 2, w = w8 & 3;
  int lane = t & 63, m = lane & 15, g = lane >> 4;

  {
    f32x4 dv = ((const f32x4*)(dst + (size_t)bh * 2048))[t];
    f32x4 uu, vv;
#pragma unroll
    for (int e = 0; e < 4; e++) {
      uu[e] = __builtin_amdgcn_exp2f(dv[e]);
      vv[e] = __builtin_amdgcn_exp2f(0.2f * dv[e]);
    }
    ((f32x4*)ul)[t] = uu;
    ((f32x4*)vl)[t] = vv;
  }

  int row_i = i0 + w * 16 + m;            // A-frag row this lane fills
  float srcL = src[(size_t)bh * 2048 + row_i];
  float Af = __builtin_amdgcn_exp2f(srcL);
  float Bf = __builtin_amdgcn_exp2f(LEAKY * srcL);

  s16x8 bones;
#pragma unroll
  for (int e = 0; e < 8; e++) bones[e] = (short)0x3F80;    // bf16 1.0

  f32x4 acc[4], accd;
#pragma unroll
  for (int db = 0; db < 4; db++) acc[db] = (f32x4){0.f, 0.f, 0.f, 0.f};
  accd = (f32x4){0.f, 0.f, 0.f, 0.f};

  char* wbase = (char*)whb4 + half * 16384;
  int ts = t & 255;
  int r_ = ts >> 2, ch_ = ts & 3;
  int jtbase = half * 16;
  const char* gbase = (const char*)(wht + (size_t)(bh * 64 + r_) * 2048) + jtbase * 128;
  int sw = (r_ & 7) << 4;
  u32x4 R0, R1;
  const u32x2* adjrow = (const u32x2*)(adjb + (size_t)row_i * 64 + jtbase * 2);

#define LOADT(jt_) { const u32x4* gp = (const u32x4*)(gbase + (jt_) * 128 + ch_ * 32); \
                     R0 = gp[0]; R1 = gp[1]; }
#define WRITET(pb_) { char* wb_ = (pb_); \
                      *(u32x4*)(wb_ + r_ * 128 + ((ch_ * 32) ^ sw)) = R0; \
                      *(u32x4*)(wb_ + r_ * 128 + ((ch_ * 32 + 16) ^ sw)) = R1; }

  LOADT(0); WRITET(wbase); LOADT(1);
  u32x2 adjw2 = adjrow[0];                // adjacency words for jt=0

  __syncthreads();                        // ul/vl + first tile visible

  for (int jt = 0; jt < 16; jt++) {
    int cur = jt & 1;
    if (jt) BAR();                        // lgkm-only barrier (no vmcnt drain)
    if (jt < 15) WRITET(wbase + (cur ^ 1) * 8192);   // tile jt+1 -> other buf
    if (jt < 14) LOADT(jt + 2);                      // issue tile jt+2 loads
    u32x2 adjnx;
    if (jt < 15) adjnx = adjrow[jt + 1];             // prefetch next adj words
    const char* wbufc = wbase + cur * 8192;
    int jglob = jtbase + jt;

#pragma unroll
    for (int ks = 0; ks < 2; ks++) {
      unsigned bits = (adjw2[ks] >> (g * 8)) & 0xffu;
      const float* up = &ul[jglob * 64 + ks * 32 + g * 8];
      const float* vp = &vl[jglob * 64 + ks * 32 + g * 8];
      f32x4 u0 = *(const f32x4*)up, u1 = *(const f32x4*)(up + 4);
      f32x4 v0 = *(const f32x4*)vp, v1 = *(const f32x4*)(vp + 4);
      float pm[8];
#pragma unroll
      for (int e = 0; e < 8; e++) {
        float ue = (e < 4) ? u0[e] : u1[e - 4];
        float ve = (e < 4) ? v0[e] : v1[e - 4];
        float p = fmaxf(Af * ue, Bf * ve);            // leaky-exp, factorized
        unsigned keep = (unsigned)(((int)(bits << (31 - e))) >> 31);
        pm[e] = __builtin_bit_cast(float, __builtin_bit_cast(unsigned, p) & keep);
      }
      u32x4 afu;
#pragma unroll
      for (int e2 = 0; e2 < 4; e2++) {
        unsigned rr_;
        asm("v_cvt_pk_bf16_f32 %0, %1, %2" : "=v"(rr_) : "v"(pm[2 * e2]), "v"(pm[2 * e2 + 1]));
        afu[e2] = rr_;
      }
      s16x8 af = __builtin_bit_cast(s16x8, afu);
#pragma unroll
      for (int db = 0; db < 4; db++) {
        int dl = db * 16 + m;
        int off = dl * 128 + ((ks * 64 + g * 16) ^ ((dl & 7) << 4));
        s16x8 bf = *(const s16x8*)(wbufc + off);
        acc[db] = __builtin_amdgcn_mfma_f32_16x16x32_bf16(af, bf, acc[db], 0, 0, 0);
      }
      accd = __builtin_amdgcn_mfma_f32_16x16x32_bf16(af, bones, accd, 0, 0, 0);
    }
    adjw2 = adjnx;
  }
#undef LOADT
#undef WRITET

  __syncthreads();                        // whb4 dead; reuse as combine buffer
  float* accl = (float*)whb4;             // [row][65] (col 64 = den)
  if (half == 1) {
#pragma unroll
    for (int db = 0; db < 4; db++)
#pragma unroll
      for (int r = 0; r < 4; r++)
        accl[(w * 16 + 4 * g + r) * 65 + db * 16 + m] = acc[db][r];
    if (m == 0) {
#pragma unroll
      for (int r = 0; r < 4; r++)
        accl[(w * 16 + 4 * g + r) * 65 + 64] = accd[r];
    }
  }
  __syncthreads();

  if (half == 0) {
#pragma unroll
    for (int db = 0; db < 4; db++)
#pragma unroll
      for (int r = 0; r < 4; r++)
        acc[db][r] += accl[(w * 16 + 4 * g + r) * 65 + db * 16 + m];
    float inv[4];
#pragma unroll
    for (int r = 0; r < 4; r++) {
      float dtot = accd[r] + accl[(w * 16 + 4 * g + r) * 65 + 64];
      inv[r] = dtot > 0.f ? 1.0f / dtot : 0.f;  // all-masked row -> zeros
    }

    float sums[4] = {0.f, 0.f, 0.f, 0.f}, sqs[4] = {0.f, 0.f, 0.f, 0.f};
#pragma unroll
    for (int r = 0; r < 4; r++) {
      int n = i0 + w * 16 + 4 * g + r;
#pragma unroll
      for (int db = 0; db < 4; db++) {
        float val = acc[db][r] * inv[r];
        hnew[(size_t)(b * 2048 + n) * 256 + hh * 64 + db * 16 + m] = val;
        sums[db] += val;
        sqs[db] += val * val;
      }
    }
#pragma unroll
    for (int db = 0; db < 4; db++) {
      sums[db] += __shfl_xor(sums[db], 16); sums[db] += __shfl_xor(sums[db], 32);
      sqs[db]  += __shfl_xor(sqs[db], 16);  sqs[db]  += __shfl_xor(sqs[db], 32);
    }
    if (g == 0) {
#pragma unroll
      for (int db = 0; db < 4; db++) {
        redS[w * 64 + db * 16 + m] = sums[db];
        redQ[w * 64 + db * 16 + m] = sqs[db];
      }
    }
  }
  __syncthreads();
  if (t < 64) {
    float ts2 = redS[t] + redS[64 + t] + redS[128 + t] + redS[192 + t];
    float tq = redQ[t] + redQ[64 + t] + redQ[128 + t] + redQ[192 + t];
    atomicAdd(&chsum[hh * 64 + t], ts2);
    atomicAdd(&chsq[hh * 64 + t], tq);
  }
}

// ---------------- Kernel D: BN(+stats inline) + ELU -----------------------
__global__ __launch_bounds__(256) void k_bn_elu(const float* __restrict__ hnew,
                                                const float* __restrict__ chsum,
                                                const float* __restrict__ chsq,
                                                const float* __restrict__ gamma,
                                                const float* __restrict__ beta,
                                                float* __restrict__ out) {
  int idx4 = blockIdx.x * 256 + threadIdx.x;
  f32x4 x = ((const f32x4*)hnew)[idx4];
  int c0 = (idx4 * 4) & 255;
  f32x4 s = *(const f32x4*)(chsum + c0);
  f32x4 sq = *(const f32x4*)(chsq + c0);
  f32x4 gm = *(const f32x4*)(gamma + c0);
  f32x4 bt = *(const f32x4*)(beta + c0);
  f32x4 y;
#pragma unroll
  for (int e = 0; e < 4; e++) {
    float mean = s[e] * (1.0f / 8192.0f);
    float var = sq[e] * (1.0f / 8192.0f) - mean * mean;
    float sc = gm[e] * rsqrtf(var + BNEPS);
    float v = (x[e] - mean) * sc + bt[e];
    y[e] = v > 0.f ? v : expm1f(v);
  }
  ((f32x4*)out)[idx4] = y;
}

extern "C" void kernel_launch(void* const* d_in, const int* in_sizes, int n_in,
                              void* d_out, int out_size, void* d_ws, size_t ws_size,
                              hipStream_t stream) {
  const float* h = (const float*)d_in[0];
  const float* W = (const float*)d_in[1];
  const float* a = (const float*)d_in[2];
  const float* gamma = (const float*)d_in[3];
  const float* beta = (const float*)d_in[4];
  const int* adj = (const int*)d_in[5];

  char* ws = (char*)d_ws;
  unsigned* adjb = (unsigned*)ws;                                  // 512 KB
  unsigned short* wht = (unsigned short*)(ws + (512 << 10));       // 4 MB
  float* src = (float*)(ws + (512 << 10) + (4 << 20));             // 128 KB
  float* dst = src + 16 * 2048;                                    // 128 KB
  float* chsum = dst + 16 * 2048;                                  // 256
  float* chsq = chsum + 256;                                       // 256
  float* hnew = (float*)(ws + (512 << 10) + (5 << 20));            // 8 MB

  k_pre<<<512 + (N_ * N_) / 256, 256, 0, stream>>>(adj, W, h, a, adjb, chsum,
                                                   wht, src, dst);
  k_attn<<<B_ * H_ * (N_ / 64), 512, 0, stream>>>(adjb, wht, src, dst,
                                                  hnew, chsum, chsq);
  k_bn_elu<<<(B_ * N_ * HD_) / 1024, 256, 0, stream>>>(hnew, chsum, chsq,
                                                       gamma, beta, (float*)d_out);
}